// Round 5
// baseline (153.861 us; speedup 1.0000x reference)
//
#include <hip/hip_runtime.h>
#include <hip/hip_bf16.h>

#define B_    8
#define C_    192
#define N_    3136
#define K_    9
#define OC    192
#define KDIM  384                 // 2*C
#define ROWS  (B_ * N_)           // 25088
#define BNK   (B_ * N_ * K_)      // 225792

typedef __hip_bfloat16 bf16;
using short8 = __attribute__((ext_vector_type(8))) short;
using f32x4  = __attribute__((ext_vector_type(4))) float;

__device__ inline float bf2f(bf16 v) { return __bfloat162float(v); }
__device__ inline bf16  f2bf(float v) { return __float2bfloat16(v); }

// ---------------------------------------------------------------------------
// Kernel A: transpose x,y from (B,C,N) fp32 to (B,N,C) bf16.
// x goes into the first half of h rows (h is (ROWS, 384) bf16); y into yT.
// ---------------------------------------------------------------------------
__global__ void k_transpose(const float* __restrict__ x, const float* __restrict__ y,
                            bf16* __restrict__ h, bf16* __restrict__ yT) {
    __shared__ float tile[32][33];
    int tx = threadIdx.x, ty = threadIdx.y;
    int n0 = blockIdx.x * 32, c0 = blockIdx.y * 32;
    int bz = blockIdx.z;
    int b = bz >> 1, which = bz & 1;
    const float* src = which ? y : x;
#pragma unroll
    for (int i = 0; i < 4; i++) {
        int c = c0 + ty + i * 8;
        tile[ty + i * 8][tx] = src[((size_t)b * C_ + c) * N_ + n0 + tx];
    }
    __syncthreads();
    if (which == 0) {
#pragma unroll
        for (int i = 0; i < 4; i++) {
            int n = n0 + ty + i * 8;
            h[((size_t)b * N_ + n) * KDIM + c0 + tx] = f2bf(tile[tx][ty + i * 8]);
        }
    } else {
#pragma unroll
        for (int i = 0; i < 4; i++) {
            int n = n0 + ty + i * 8;
            yT[((size_t)b * N_ + n) * C_ + c0 + tx] = f2bf(tile[tx][ty + i * 8]);
        }
    }
}

// ---------------------------------------------------------------------------
// W (OC, 384) fp32 -> bf16
// ---------------------------------------------------------------------------
__global__ void k_wprep(const float* __restrict__ W, bf16* __restrict__ Wb) {
    int i = blockIdx.x * 256 + threadIdx.x;
    if (i < OC * KDIM) Wb[i] = f2bf(W[i]);
}

// ---------------------------------------------------------------------------
// Kernel B: per row (b,n): rel[c] = max_k ( y[b, j_k, c] - x[b, i_k, c] ),
// written into the second half of h's row. One wave per row.
// ---------------------------------------------------------------------------
__global__ void k_gather_rel(const int* __restrict__ ei, bf16* __restrict__ h,
                             const bf16* __restrict__ yT) {
    int wave = threadIdx.x >> 6;
    int lane = threadIdx.x & 63;
    int r = blockIdx.x * 4 + wave;           // global row = b*N + n
    int b = r / N_;

    const int* e0 = ei + (size_t)r * K_;               // edge_index[0] -> gathers y
    const int* e1 = ei + (size_t)BNK + (size_t)r * K_; // edge_index[1] -> gathers x
    int ej[K_], eii[K_];
#pragma unroll
    for (int k = 0; k < K_; k++) { ej[k] = e0[k]; eii[k] = e1[k]; }

    const bf16* ybase = yT + (size_t)b * N_ * C_;
    const bf16* xbase = h + (size_t)b * N_ * KDIM;   // first half of h rows = x

#pragma unroll
    for (int ch = 0; ch < 3; ch++) {
        int c = ch * 64 + lane;
        float m = -3.4e38f;
#pragma unroll
        for (int k = 0; k < K_; k++) {
            float vy = bf2f(ybase[(size_t)ej[k] * C_ + c]);
            float vx = bf2f(xbase[(size_t)eii[k] * KDIM + c]);
            m = fmaxf(m, vy - vx);
        }
        h[(size_t)r * KDIM + C_ + c] = f2bf(m);
    }
}

// ---------------------------------------------------------------------------
// Kernel C: GEMM out_pre[(b,n), o] = sum_k h[(b,n),k] * W[o,k]
// 3 waves/block, block tile 64 rows x 192 cols, K=384 in 12 steps of 32.
// Epilogue: store fp32 + per-channel sum/sumsq atomics for BN.
// ---------------------------------------------------------------------------
__launch_bounds__(192)
__global__ void k_gemm(const bf16* __restrict__ h, const bf16* __restrict__ Wb,
                       float* __restrict__ outp, float* __restrict__ stats) {
    int tid = threadIdx.x;
    int wave = tid >> 6, lane = tid & 63;
    int fcol = lane & 15, fgrp = lane >> 4;
    int r0 = blockIdx.x * 64;
    int colbase = wave * 64;

    f32x4 acc[4][4] = {};

    for (int kk = 0; kk < 12; kk++) {
        short8 a[4], bb[4];
#pragma unroll
        for (int i = 0; i < 4; i++)
            a[i] = *reinterpret_cast<const short8*>(
                h + (size_t)(r0 + i * 16 + fcol) * KDIM + kk * 32 + fgrp * 8);
#pragma unroll
        for (int j = 0; j < 4; j++)
            bb[j] = *reinterpret_cast<const short8*>(
                Wb + (size_t)(colbase + j * 16 + fcol) * KDIM + kk * 32 + fgrp * 8);
#pragma unroll
        for (int i = 0; i < 4; i++)
#pragma unroll
            for (int j = 0; j < 4; j++)
                acc[i][j] = __builtin_amdgcn_mfma_f32_16x16x32_bf16(a[i], bb[j], acc[i][j], 0, 0, 0);
    }

#pragma unroll
    for (int j = 0; j < 4; j++) {
        int o = colbase + j * 16 + fcol;
        float s1 = 0.f, s2 = 0.f;
#pragma unroll
        for (int i = 0; i < 4; i++) {
            int rbase = r0 + i * 16 + fgrp * 4;
#pragma unroll
            for (int e = 0; e < 4; e++) {
                float v = acc[i][j][e];
                outp[(size_t)(rbase + e) * OC + o] = v;
                s1 += v;
                s2 += v * v;
            }
        }
        s1 += __shfl_xor(s1, 16); s1 += __shfl_xor(s1, 32);
        s2 += __shfl_xor(s2, 16); s2 += __shfl_xor(s2, 32);
        if (fgrp == 0) {
            atomicAdd(&stats[o], s1);
            atomicAdd(&stats[OC + o], s2);
        }
    }
}

// ---------------------------------------------------------------------------
// Kernel D: BN (batch stats) + exact GELU, with (bn,o) -> (b,o,n) transpose.
// ---------------------------------------------------------------------------
__global__ void k_bn_gelu(const float* __restrict__ outp, const float* __restrict__ stats,
                          const float* __restrict__ gamma, const float* __restrict__ beta,
                          float* __restrict__ out) {
    __shared__ float tile[32][33];
    int tx = threadIdx.x, ty = threadIdx.y;
    int n0 = blockIdx.x * 32, o0 = blockIdx.y * 32, b = blockIdx.z;
#pragma unroll
    for (int i = 0; i < 4; i++) {
        int n = n0 + ty + i * 8;
        tile[ty + i * 8][tx] = outp[(size_t)(b * N_ + n) * OC + o0 + tx];
    }
    __syncthreads();
    const float invc = 1.0f / (float)ROWS;
#pragma unroll
    for (int i = 0; i < 4; i++) {
        int o = o0 + ty + i * 8;
        float mean = stats[o] * invc;
        float var  = stats[OC + o] * invc - mean * mean;
        float is   = rsqrtf(var + 1e-5f);
        float g = gamma[o], bt = beta[o];
        float v = tile[tx][ty + i * 8];
        float z = (v - mean) * is * g + bt;
        float gl = 0.5f * z * (1.0f + erff(z * 0.70710678118654752f));
        out[((size_t)b * OC + o) * N_ + n0 + tx] = gl;
    }
}

// ---------------------------------------------------------------------------
extern "C" void kernel_launch(void* const* d_in, const int* in_sizes, int n_in,
                              void* d_out, int out_size, void* d_ws, size_t ws_size,
                              hipStream_t stream) {
    const float* x     = (const float*)d_in[0];
    const float* y     = (const float*)d_in[1];
    const int*   ei    = (const int*)d_in[2];
    const float* W     = (const float*)d_in[3];
    const float* gamma = (const float*)d_in[4];
    const float* beta  = (const float*)d_in[5];
    float* out = (float*)d_out;

    char* ws = (char*)d_ws;
    // layout (256B-aligned):
    //   h     : ROWS*384 bf16  = 19,267,584 B   (first half x, second half rel)
    //   yT    : ROWS*192 bf16  =  9,633,792 B
    //   Wb    : 192*384  bf16  =    147,456 B
    //   outp  : ROWS*192 fp32  = 19,267,584 B
    //   stats : 384 fp32       =      1,536 B
    bf16*  h     = (bf16*)(ws);
    bf16*  yT    = (bf16*)(ws + 19267584);
    bf16*  Wb    = (bf16*)(ws + 19267584 + 9633792);
    float* outp  = (float*)(ws + 29048832);
    float* stats = (float*)(ws + 48316416);

    hipMemsetAsync(stats, 0, 2 * OC * sizeof(float), stream);

    dim3 bt(32, 8);
    k_transpose<<<dim3(N_ / 32, C_ / 32, 2 * B_), bt, 0, stream>>>(x, y, h, yT);
    k_wprep<<<(OC * KDIM + 255) / 256, 256, 0, stream>>>(W, Wb);
    k_gather_rel<<<ROWS / 4, 256, 0, stream>>>(ei, h, yT);
    k_gemm<<<ROWS / 64, 192, 0, stream>>>(h, Wb, outp, stats);
    k_bn_gelu<<<dim3(N_ / 32, OC / 32, B_), bt, 0, stream>>>(outp, stats, gamma, beta, out);
}